// Round 1
// baseline (2834.632 us; speedup 1.0000x reference)
//
#include <hip/hip_runtime.h>
#include <hip/hip_bf16.h>
#include <stdint.h>

#define T_STEPS 64
#define BATCH   512
#define SDIM    10
#define HDIM    1024
#define GDIM    4096   // 4*H

typedef __attribute__((ext_vector_type(8))) short bf16x8;
typedef __attribute__((ext_vector_type(4))) float f32x4;

__device__ __forceinline__ float sigmoidf_(float x) { return 1.0f / (1.0f + __expf(-x)); }

// ---------------------------------------------------------------------------
// Setup: convert W_hh -> bf16 (B^T layout already: [4H][H], K contiguous),
// zero h0 and c0. Runs every call (ws is re-poisoned).
// ---------------------------------------------------------------------------
__global__ void setup_kernel(const float* __restrict__ W_hh,
                             __hip_bfloat16* __restrict__ whh_bf,
                             __hip_bfloat16* __restrict__ h0,
                             float* __restrict__ c0) {
    int idx = blockIdx.x * blockDim.x + threadIdx.x;
    int stride = gridDim.x * blockDim.x;
    for (int i = idx; i < GDIM * HDIM; i += stride)
        whh_bf[i] = __float2bfloat16(W_hh[i]);
    for (int i = idx; i < BATCH * HDIM; i += stride)
        h0[i] = __float2bfloat16(0.0f);
    for (int i = idx; i < BATCH * HDIM; i += stride)
        c0[i] = 0.0f;
}

// ---------------------------------------------------------------------------
// Weq[s][n] = sum_k W_in[s][k] * W_ih[n][k]   (fp32, exact input-path folding)
// beq[n]   = b_ih[n] + b_hh[n] + sum_k b_in[k] * W_ih[n][k]
// One wave per n (4096 waves).
// ---------------------------------------------------------------------------
__global__ void weq_kernel(const float* __restrict__ W_in,
                           const float* __restrict__ W_ih,
                           const float* __restrict__ b_in,
                           const float* __restrict__ b_ih,
                           const float* __restrict__ b_hh,
                           float* __restrict__ Weq,
                           float* __restrict__ beq) {
    int gw = (blockIdx.x * blockDim.x + threadIdx.x) >> 6;  // wave id == n
    int lane = threadIdx.x & 63;
    if (gw >= GDIM) return;
    float acc[SDIM + 1];
#pragma unroll
    for (int s = 0; s <= SDIM; s++) acc[s] = 0.0f;
    for (int it = 0; it < HDIM / 64; ++it) {
        int k = lane + it * 64;
        float w = W_ih[gw * HDIM + k];
#pragma unroll
        for (int s = 0; s < SDIM; s++) acc[s] += w * W_in[s * HDIM + k];
        acc[SDIM] += w * b_in[k];
    }
#pragma unroll
    for (int s = 0; s <= SDIM; s++) {
        float v = acc[s];
        for (int off = 32; off > 0; off >>= 1) v += __shfl_down(v, off);
        acc[s] = v;
    }
    if (lane == 0) {
#pragma unroll
        for (int s = 0; s < SDIM; s++) Weq[s * GDIM + gw] = acc[s];
        beq[gw] = acc[SDIM] + b_ih[gw] + b_hh[gw];
    }
}

// ---------------------------------------------------------------------------
// One LSTM timestep, fully fused:
//   gates[b, gate*H + h] = h_prev @ W_hh^T (bf16 MFMA)  + inputs[t] @ Weq + beq
//   cell nonlinearity + c/h update in epilogue.
// BM=64 rows of b, BN=128 cols = 4 gates x 32 h. BK=64. 256 threads (4 waves,
// each wave owns one gate's 32-col quadrant). Grid (8, 32) = 256 blocks.
// LDS: sA [64][64] bf16 (8KB) | sB [128][64] bf16 (16KB) | G [64][128] f32 (32KB)
// XOR swizzle: phys_byte_in_row = logical_byte ^ ((row&7)<<4)  (balanced banks)
// ---------------------------------------------------------------------------
__launch_bounds__(256)
__global__ void step_kernel(const float* __restrict__ inputs,          // [T,B,S]
                            const float* __restrict__ Weq,             // [S][4096]
                            const float* __restrict__ beq,             // [4096]
                            const __hip_bfloat16* __restrict__ whh,    // [4096][1024] bf16
                            const __hip_bfloat16* __restrict__ h_prev, // [512][1024] bf16
                            __hip_bfloat16* __restrict__ h_next,       // [512][1024] bf16
                            float* __restrict__ c_buf,                 // [512][1024] f32
                            __hip_bfloat16* __restrict__ hs,           // [T][B][H] bf16
                            int t) {
    __shared__ __align__(16) unsigned char lds[57344];
    float* G = (float*)(lds + 24576);

    const int tid = threadIdx.x;
    const int w = tid >> 6;
    const int lane = tid & 63;
    const int m0 = blockIdx.x * 64;   // batch-row block
    const int h0 = blockIdx.y * 32;   // h block

    // --- staging assignments (16B chunks). A: 512 chunks, B: 1024 chunks ---
    int a_row[2], a_cl[2];
#pragma unroll
    for (int i = 0; i < 2; i++) { int q = tid + i * 256; a_row[i] = q >> 3; a_cl[i] = q & 7; }
    int b_row[4], b_cl[4], b_wr[4];
#pragma unroll
    for (int i = 0; i < 4; i++) {
        int q = tid + i * 256;
        b_row[i] = q >> 3; b_cl[i] = q & 7;
        b_wr[i] = (b_row[i] >> 5) * HDIM + h0 + (b_row[i] & 31);  // gate*H + h0 + hoff
    }

    uint4 ra[2], rb[4];
#pragma unroll
    for (int i = 0; i < 2; i++)
        ra[i] = *(const uint4*)(h_prev + (m0 + a_row[i]) * HDIM + (a_cl[i] << 3));
#pragma unroll
    for (int i = 0; i < 4; i++)
        rb[i] = *(const uint4*)(whh + b_wr[i] * HDIM + (b_cl[i] << 3));

    f32x4 acc[4][2];
#pragma unroll
    for (int m = 0; m < 4; m++)
#pragma unroll
        for (int n = 0; n < 2; n++) acc[m][n] = (f32x4){0.f, 0.f, 0.f, 0.f};

    const int lr = lane & 15, lk = lane >> 4;

    for (int kt = 0; kt < HDIM / 64; ++kt) {
        __syncthreads();  // previous iter's LDS reads complete
#pragma unroll
        for (int i = 0; i < 2; i++)
            *(uint4*)(lds + a_row[i] * 128 + ((a_cl[i] << 4) ^ ((a_row[i] & 7) << 4))) = ra[i];
#pragma unroll
        for (int i = 0; i < 4; i++)
            *(uint4*)(lds + 8192 + b_row[i] * 128 + ((b_cl[i] << 4) ^ ((b_row[i] & 7) << 4))) = rb[i];
        __syncthreads();
        if (kt < HDIM / 64 - 1) {  // prefetch next K tile (overlaps MFMA below)
            int ko = (kt + 1) * 64;
#pragma unroll
            for (int i = 0; i < 2; i++)
                ra[i] = *(const uint4*)(h_prev + (m0 + a_row[i]) * HDIM + ko + (a_cl[i] << 3));
#pragma unroll
            for (int i = 0; i < 4; i++)
                rb[i] = *(const uint4*)(whh + b_wr[i] * HDIM + ko + (b_cl[i] << 3));
        }
#pragma unroll
        for (int kk = 0; kk < 2; ++kk) {
            bf16x8 af[4], bfr[2];
            const int byteoff = kk * 64 + lk * 16;
#pragma unroll
            for (int m = 0; m < 4; m++) {
                int r = m * 16 + lr;
                af[m] = *(const bf16x8*)(lds + r * 128 + (byteoff ^ ((r & 7) << 4)));
            }
#pragma unroll
            for (int n = 0; n < 2; n++) {
                int r = w * 32 + n * 16 + lr;
                bfr[n] = *(const bf16x8*)(lds + 8192 + r * 128 + (byteoff ^ ((r & 7) << 4)));
            }
#pragma unroll
            for (int m = 0; m < 4; m++)
#pragma unroll
                for (int n = 0; n < 2; n++)
                    acc[m][n] = __builtin_amdgcn_mfma_f32_16x16x32_bf16(af[m], bfr[n], acc[m][n], 0, 0, 0);
        }
    }

    // --- write gates to LDS (C/D layout: col=lane&15, row=(lane>>4)*4+reg) ---
#pragma unroll
    for (int m = 0; m < 4; m++)
#pragma unroll
        for (int n = 0; n < 2; n++)
#pragma unroll
            for (int r = 0; r < 4; r++) {
                int row = m * 16 + lk * 4 + r;
                int col = w * 32 + n * 16 + lr;
                G[row * 128 + col] = acc[m][n][r];
            }
    __syncthreads();

    // --- fused LSTM cell: add input-path (K=10) + nonlinearity + c/h update ---
#pragma unroll
    for (int j = 0; j < 8; j++) {
        int p = tid + j * 256;
        int bl = p >> 5, hf = p & 31;
        int bg = m0 + bl, hg = h0 + hf;
        const float* inp = inputs + (t * BATCH + bg) * SDIM;
        float xv[SDIM];
#pragma unroll
        for (int s = 0; s < SDIM; s++) xv[s] = inp[s];
        float pre[4];
#pragma unroll
        for (int gate = 0; gate < 4; ++gate) {
            int n = gate * HDIM + hg;
            float xc = beq[n];
#pragma unroll
            for (int s = 0; s < SDIM; s++) xc += xv[s] * Weq[s * GDIM + n];
            pre[gate] = G[bl * 128 + gate * 32 + hf] + xc;
        }
        float ig = sigmoidf_(pre[0]);
        float fg = sigmoidf_(pre[1]);
        float gg = tanhf(pre[2]);
        float og = sigmoidf_(pre[3]);
        float co = c_buf[bg * HDIM + hg];
        float cn = fg * co + ig * gg;
        float hn = og * tanhf(cn);
        c_buf[bg * HDIM + hg] = cn;
        __hip_bfloat16 hb = __float2bfloat16(hn);
        h_next[bg * HDIM + hg] = hb;
        hs[(t * BATCH + bg) * HDIM + hg] = hb;
    }
}

// ---------------------------------------------------------------------------
// out[b, t, s] = sum_h hs[t,b,h] * W_out[h,s] + b_out[s]
// One wave per (t,b) row. W_out transposed into LDS once per block.
// ---------------------------------------------------------------------------
__launch_bounds__(256)
__global__ void out_kernel(const __hip_bfloat16* __restrict__ hs,
                           const float* __restrict__ W_out,
                           const float* __restrict__ b_out,
                           float* __restrict__ out) {
    __shared__ float WoT[SDIM][HDIM];  // 40KB, transposed
    const int tid = threadIdx.x;
    for (int i = tid; i < HDIM * SDIM; i += 256) {
        int h = i / SDIM, s = i % SDIM;
        WoT[s][h] = W_out[i];
    }
    __syncthreads();

    const int row = blockIdx.x * 4 + (tid >> 6);  // 0..32767 == t*512+b
    const int lane = tid & 63;
    const int tt = row >> 9, b = row & 511;
    const __hip_bfloat16* hrow = hs + row * HDIM;

    float acc[SDIM];
#pragma unroll
    for (int s = 0; s < SDIM; s++) acc[s] = 0.0f;

    for (int it = 0; it < HDIM / 128; ++it) {
        int h = (lane + it * 64) * 2;
        uint32_t v = *(const uint32_t*)(&hrow[h]);
        float f0 = __uint_as_float(v << 16);
        float f1 = __uint_as_float(v & 0xffff0000u);
#pragma unroll
        for (int s = 0; s < SDIM; s++) {
            float2 wv = *(const float2*)(&WoT[s][h]);
            acc[s] += f0 * wv.x + f1 * wv.y;
        }
    }
#pragma unroll
    for (int s = 0; s < SDIM; s++) {
        float v = acc[s];
        for (int off = 32; off > 0; off >>= 1) v += __shfl_down(v, off);
        acc[s] = v;
    }
    if (lane == 0) {
#pragma unroll
        for (int s = 0; s < SDIM; s++)
            out[b * (T_STEPS * SDIM) + tt * SDIM + s] = acc[s] + b_out[s];
    }
}

// ---------------------------------------------------------------------------
extern "C" void kernel_launch(void* const* d_in, const int* in_sizes, int n_in,
                              void* d_out, int out_size, void* d_ws, size_t ws_size,
                              hipStream_t stream) {
    const float* inputs = (const float*)d_in[0];
    const float* W_in   = (const float*)d_in[1];
    const float* b_in   = (const float*)d_in[2];
    const float* W_ih   = (const float*)d_in[3];
    const float* W_hh   = (const float*)d_in[4];
    const float* b_ih   = (const float*)d_in[5];
    const float* b_hh   = (const float*)d_in[6];
    const float* W_out  = (const float*)d_in[7];
    const float* b_out  = (const float*)d_in[8];
    float* out = (float*)d_out;

    uint8_t* ws = (uint8_t*)d_ws;
    __hip_bfloat16* whh_bf = (__hip_bfloat16*)(ws);                 //  8 MB
    __hip_bfloat16* hbuf0  = (__hip_bfloat16*)(ws + 8388608);       //  1 MB
    __hip_bfloat16* hbuf1  = (__hip_bfloat16*)(ws + 9437184);       //  1 MB
    float*          c_buf  = (float*)(ws + 10485760);               //  2 MB
    __hip_bfloat16* hs     = (__hip_bfloat16*)(ws + 12582912);      // 64 MB
    float*          Weq    = (float*)(ws + 79691776);               // 160 KB
    float*          beq    = (float*)(ws + 79855616);               //  16 KB

    setup_kernel<<<2048, 256, 0, stream>>>(W_hh, whh_bf, hbuf0, c_buf);
    weq_kernel<<<1024, 256, 0, stream>>>(W_in, W_ih, b_in, b_ih, b_hh, Weq, beq);
    for (int t = 0; t < T_STEPS; t++) {
        const __hip_bfloat16* hp = (t & 1) ? hbuf1 : hbuf0;
        __hip_bfloat16*       hn = (t & 1) ? hbuf0 : hbuf1;
        step_kernel<<<dim3(8, 32), 256, 0, stream>>>(inputs, Weq, beq, whh_bf,
                                                     hp, hn, c_buf, hs, t);
    }
    out_kernel<<<8192, 256, 0, stream>>>(hs, W_out, b_out, out);
}